// Round 4
// baseline (225.972 us; speedup 1.0000x reference)
//
#include <hip/hip_runtime.h>
#include <hip/hip_bf16.h>

#define B_    32
#define LD_   512
#define LQ_   32
#define E_    300
#define NF_   4
#define D_    304
#define M_    16
#define ALPHA_ 0.9f
#define CIN_  1212          // 3*D + E
#define KP1_  1280          // CIN padded to multiple of 128
#define NCOL_ 1056          // 33 columns * 32 batches
#define NPAD_ 1088          // 17 * 64
#define PPL_  9
#define NEG_N_ 128

typedef short short8 __attribute__((ext_vector_type(8)));
typedef float f32x4 __attribute__((ext_vector_type(4)));

__device__ __forceinline__ unsigned short f2bf(float f) {
    unsigned int x = __float_as_uint(f);
    unsigned int r = (x + 0x7FFFu + ((x >> 16) & 1u)) >> 16;
    return (unsigned short)r;
}
__device__ __forceinline__ float bf2f(unsigned short u) {
    return __uint_as_float(((unsigned int)u) << 16);
}

// ---------------------------------------------------------------------------
// Mega-prep kernel, branch by blockIdx.x:
//   [0, 1056)      : build feature column (query FOFE inlined)
//   [1056, 2000)   : fp32->bf16 weight conversion (grid-stride)
//   [2000, 2032)   : zero Ft pad rows 1056..1087
//   2032           : zero zbuf[0..1087]
// ---------------------------------------------------------------------------
__global__ __launch_bounds__(320) void prep(
    const int* __restrict__ doc, const float* __restrict__ doc_f,
    const int* __restrict__ query,
    const int* __restrict__ target_s, const int* __restrict__ target_e,
    const float* __restrict__ emb,
    const int* __restrict__ rand_length, const int* __restrict__ rand_position,
    const float* __restrict__ W1, const float* __restrict__ W2,
    const float* __restrict__ W3, const float* __restrict__ W4,
    unsigned short* __restrict__ W1b, unsigned short* __restrict__ W2b,
    unsigned short* __restrict__ W3b, unsigned short* __restrict__ W4b,
    unsigned short* __restrict__ Ft, float* __restrict__ zbuf)
{
    int bid = blockIdx.x;
    int tid = threadIdx.x;

    if (bid < NCOL_) {
        int b = bid / 33;
        int col = bid % 33;
        __shared__ int   s_t[3][16];
        __shared__ float s_w[3][16];
        __shared__ int   s_row[3][16];
        if (tid < 48) {
            int part = tid >> 4, k = tid & 15;
            int t; float valid;
            if (col == 0) {
                int ts = target_s[b], te = target_e[b];
                int span = te - ts;
                if (part == 0)      { t = ts - 1 - k;  valid = (t >= 0) ? 1.f : 0.f; }
                else if (part == 1) { t = te - k;      valid = (k <= span && t >= 0) ? 1.f : 0.f; }
                else                { t = te + 1 + k;  valid = (t < LD_) ? 1.f : 0.f; }
            } else {
                int j = col - 1;
                int r = j / PPL_, p = j - r * PPL_;
                int rl = rand_length[r];
                int rp = rand_position[r * PPL_ + p];
                if (part == 0)      { t = rp - 1 - k;      valid = (t >= 0) ? 1.f : 0.f; }
                else if (part == 1) { t = rp - k;          valid = (k <= rl && t >= 0) ? 1.f : 0.f; }
                else                { t = rp + rl + 1 + k; valid = (t < LD_) ? 1.f : 0.f; }
            }
            float w = (valid != 0.f) ? powf(ALPHA_, (float)k) : 0.f;
            t = min(max(t, 0), LD_ - 1);
            s_t[part][k] = t;
            s_w[part][k] = w;
            s_row[part][k] = doc[b * LD_ + t];
        }
        __syncthreads();

        unsigned short* out = Ft + (size_t)bid * KP1_;
        int g = tid;                       // 320 groups of 4 elements (K=1280)
        if (g < 228) {                     // doc parts: 3 * 76 groups
            int part = g / 76;
            int g2 = g - part * 76;
            int cc = g2 * 4;
            float ax = 0.f, ay = 0.f, az = 0.f, aw = 0.f;
            if (cc < 300) {
                for (int i = 0; i < 16; ++i) {
                    float4 v = *(const float4*)(emb + (size_t)s_row[part][i] * E_ + cc);
                    float wv = s_w[part][i];
                    ax += wv * v.x; ay += wv * v.y; az += wv * v.z; aw += wv * v.w;
                }
            } else {
                for (int i = 0; i < 16; ++i) {
                    float4 v = *(const float4*)(doc_f + ((size_t)b * LD_ + s_t[part][i]) * NF_);
                    float wv = s_w[part][i];
                    ax += wv * v.x; ay += wv * v.y; az += wv * v.z; aw += wv * v.w;
                }
            }
            ushort4 o; o.x = f2bf(ax); o.y = f2bf(ay); o.z = f2bf(az); o.w = f2bf(aw);
            *(ushort4*)(out + 4 * g) = o;
        } else if (g < 303) {              // query FOFE, ce = (g-228)*4
            int ce = (g - 228) * 4;
            float ax = 0.f, ay = 0.f, az = 0.f, aw = 0.f;
            float wv = powf(ALPHA_, (float)(LQ_ - 1));
            for (int i = 0; i < 32; ++i) {
                int row = query[b * LQ_ + i];
                float4 v = *(const float4*)(emb + (size_t)row * E_ + ce);
                ax += wv * v.x; ay += wv * v.y; az += wv * v.z; aw += wv * v.w;
                wv *= (1.0f / ALPHA_);
            }
            ushort4 o; o.x = f2bf(ax); o.y = f2bf(ay); o.z = f2bf(az); o.w = f2bf(aw);
            *(ushort4*)(out + 4 * g) = o;
        } else {                           // K padding 1212..1279
            ushort4 z; z.x = 0; z.y = 0; z.z = 0; z.w = 0;
            *(ushort4*)(out + 4 * g) = z;
        }
    } else if (bid < 2000) {
        // weight conversion, grid-stride over ushort4 groups
        const long n1 = 1024L * (KP1_ / 4);          // 327680 (W1 K-padded)
        const long n2 = 1024L * 1024L / 4;           // 262144
        const long n4 = 512L * 1024L / 4;            // 131072
        const long total = n1 + 2 * n2 + n4;         // 983040
        long stride = 944L * 320L;
        for (long i = (long)(bid - NCOL_) * 320L + tid; i < total; i += stride) {
            ushort4 o;
            if (i < n1) {
                long m = i / 320; int k4 = (int)(i - m * 320);
                if (k4 < 303) {
                    float4 v = *(const float4*)(W1 + m * CIN_ + k4 * 4);
                    o.x = f2bf(v.x); o.y = f2bf(v.y); o.z = f2bf(v.z); o.w = f2bf(v.w);
                } else { o.x = 0; o.y = 0; o.z = 0; o.w = 0; }
                *(ushort4*)(W1b + i * 4) = o;
            } else if (i < n1 + n2) {
                long j = i - n1;
                float4 v = *(const float4*)(W2 + j * 4);
                o.x = f2bf(v.x); o.y = f2bf(v.y); o.z = f2bf(v.z); o.w = f2bf(v.w);
                *(ushort4*)(W2b + j * 4) = o;
            } else if (i < n1 + 2 * n2) {
                long j = i - n1 - n2;
                float4 v = *(const float4*)(W3 + j * 4);
                o.x = f2bf(v.x); o.y = f2bf(v.y); o.z = f2bf(v.z); o.w = f2bf(v.w);
                *(ushort4*)(W3b + j * 4) = o;
            } else {
                long j = i - n1 - 2 * n2;
                float4 v = *(const float4*)(W4 + j * 4);
                o.x = f2bf(v.x); o.y = f2bf(v.y); o.z = f2bf(v.z); o.w = f2bf(v.w);
                *(ushort4*)(W4b + j * 4) = o;
            }
        }
    } else if (bid < 2032) {
        int row = NCOL_ + (bid - 2000);
        ushort4 z; z.x = 0; z.y = 0; z.z = 0; z.w = 0;
        *(ushort4*)(Ft + (size_t)row * KP1_ + tid * 4) = z;
    } else {
        for (int i = tid; i < NPAD_; i += 320) zbuf[i] = 0.f;
    }
}

// ---------------------------------------------------------------------------
// Shared GEMM core: 64x64 tile, BK=128, single LDS buffer + register
// prefetch, 4-wave in-kernel K-split (wave w owns k32 window w*32), each
// wave computes the FULL 64x64 via 4x4 of 16x16x32 MFMA. Cross-wave
// reduction through LDS scratch (union). K multiple of 128.
// ---------------------------------------------------------------------------
#define GEMM_CORE(A_, B_PTR_, M_ARG_, K_ARG_)                                 \
    int tid = threadIdx.x, lane = tid & 63, w = tid >> 6;                     \
    int m0 = blockIdx.x * 64, n0 = blockIdx.y * 64;                           \
    int fr = lane & 15, fq = lane >> 4, fk = fq * 8, kw = w * 32;             \
    int ar = tid >> 2, ac = (tid & 3) * 32;                                   \
    const unsigned short* Ag = (A_) + (size_t)(m0 + ar) * (K_ARG_) + ac;      \
    const unsigned short* Bg = (B_PTR_) + (size_t)(n0 + ar) * (K_ARG_) + ac;  \
    f32x4 acc[16];                                                            \
    _Pragma("unroll")                                                         \
    for (int t = 0; t < 16; ++t) { acc[t][0]=0.f; acc[t][1]=0.f; acc[t][2]=0.f; acc[t][3]=0.f; } \
    int nk = (K_ARG_) >> 7;                                                   \
    uint4 pa0, pa1, pa2, pa3, pb0, pb1, pb2, pb3;                             \
    pa0 = *(const uint4*)(Ag);      pa1 = *(const uint4*)(Ag + 8);            \
    pa2 = *(const uint4*)(Ag + 16); pa3 = *(const uint4*)(Ag + 24);           \
    pb0 = *(const uint4*)(Bg);      pb1 = *(const uint4*)(Bg + 8);            \
    pb2 = *(const uint4*)(Bg + 16); pb3 = *(const uint4*)(Bg + 24);           \
    for (int i = 0; i < nk; ++i) {                                            \
        *(uint4*)&sh.s.A[ar][ac]      = pa0;                                  \
        *(uint4*)&sh.s.A[ar][ac + 8]  = pa1;                                  \
        *(uint4*)&sh.s.A[ar][ac + 16] = pa2;                                  \
        *(uint4*)&sh.s.A[ar][ac + 24] = pa3;                                  \
        *(uint4*)&sh.s.B[ar][ac]      = pb0;                                  \
        *(uint4*)&sh.s.B[ar][ac + 8]  = pb1;                                  \
        *(uint4*)&sh.s.B[ar][ac + 16] = pb2;                                  \
        *(uint4*)&sh.s.B[ar][ac + 24] = pb3;                                  \
        __syncthreads();                                                      \
        if (i + 1 < nk) {                                                     \
            const unsigned short* An = Ag + (size_t)(i + 1) * 128;            \
            const unsigned short* Bn = Bg + (size_t)(i + 1) * 128;            \
            pa0 = *(const uint4*)(An);      pa1 = *(const uint4*)(An + 8);    \
            pa2 = *(const uint4*)(An + 16); pa3 = *(const uint4*)(An + 24);   \
            pb0 = *(const uint4*)(Bn);      pb1 = *(const uint4*)(Bn + 8);    \
            pb2 = *(const uint4*)(Bn + 16); pb3 = *(const uint4*)(Bn + 24);   \
        }                                                                     \
        short8 af[4], bfr[4];                                                 \
        _Pragma("unroll")                                                     \
        for (int mt = 0; mt < 4; ++mt)                                        \
            af[mt] = *(const short8*)&sh.s.A[mt * 16 + fr][kw + fk];          \
        _Pragma("unroll")                                                     \
        for (int nt = 0; nt < 4; ++nt)                                        \
            bfr[nt] = *(const short8*)&sh.s.B[nt * 16 + fr][kw + fk];         \
        _Pragma("unroll")                                                     \
        for (int mt = 0; mt < 4; ++mt)                                        \
            _Pragma("unroll")                                                 \
            for (int nt = 0; nt < 4; ++nt)                                    \
                acc[mt * 4 + nt] = __builtin_amdgcn_mfma_f32_16x16x32_bf16(   \
                    af[mt], bfr[nt], acc[mt * 4 + nt], 0, 0, 0);              \
        __syncthreads();                                                      \
    }                                                                         \
    /* cross-wave reduction: waves 1,3 dump; 0,2 add; wave 2 dumps; 0 adds */ \
    if (w == 1 || w == 3) {                                                   \
        int r = w >> 1;                                                       \
        _Pragma("unroll")                                                     \
        for (int t = 0; t < 16; ++t) *(f32x4*)&sh.red[r][t][lane][0] = acc[t];\
    }                                                                         \
    __syncthreads();                                                          \
    if (w == 0 || w == 2) {                                                   \
        int r = w >> 1;                                                       \
        _Pragma("unroll")                                                     \
        for (int t = 0; t < 16; ++t) {                                        \
            f32x4 v = *(const f32x4*)&sh.red[r][t][lane][0];                  \
            acc[t][0]+=v[0]; acc[t][1]+=v[1]; acc[t][2]+=v[2]; acc[t][3]+=v[3]; \
        }                                                                     \
    }                                                                         \
    __syncthreads();                                                          \
    if (w == 2) {                                                             \
        _Pragma("unroll")                                                     \
        for (int t = 0; t < 16; ++t) *(f32x4*)&sh.red[0][t][lane][0] = acc[t];\
    }                                                                         \
    __syncthreads();

union GemmLds {
    struct { unsigned short A[64][136]; unsigned short B[64][136]; } s;  // 34816 B
    float red[2][16][64][4];                                             // 32768 B
};

// Layers 1-3: C[n][m] = relu(A·B^T) in bf16
__global__ __launch_bounds__(256) void gemm_relu(
    const unsigned short* __restrict__ A,
    const unsigned short* __restrict__ Bm,
    unsigned short* __restrict__ C, int M, int K)
{
    __shared__ GemmLds sh;
    GEMM_CORE(A, Bm, M, K)
    if (w == 0) {
        #pragma unroll
        for (int t = 0; t < 16; ++t) {
            f32x4 v = *(const f32x4*)&sh.red[0][t][lane][0];
            f32x4 s = acc[t];
            s[0]+=v[0]; s[1]+=v[1]; s[2]+=v[2]; s[3]+=v[3];
            int m = m0 + (t >> 2) * 16 + fq * 4;
            int n = n0 + (t & 3) * 16 + fr;
            ushort4 o;
            o.x = f2bf(fmaxf(s[0], 0.f));
            o.y = f2bf(fmaxf(s[1], 0.f));
            o.z = f2bf(fmaxf(s[2], 0.f));
            o.w = f2bf(fmaxf(s[3], 0.f));
            *(ushort4*)(C + (size_t)n * M + m) = o;
        }
    }
}

// Layer 4 + score partials: z[n] += sum_m relu(h4[m][n]) * W5[m]
__global__ __launch_bounds__(256) void gemm4_score(
    const unsigned short* __restrict__ A,
    const unsigned short* __restrict__ Bm,
    const float* __restrict__ W5, float* __restrict__ zbuf, int M, int K)
{
    __shared__ GemmLds sh;
    GEMM_CORE(A, Bm, M, K)
    if (w == 0) {
        #pragma unroll
        for (int t = 0; t < 16; ++t) {
            f32x4 v = *(const f32x4*)&sh.red[0][t][lane][0];
            f32x4 s = acc[t];
            s[0]+=v[0]; s[1]+=v[1]; s[2]+=v[2]; s[3]+=v[3];
            int m = m0 + (t >> 2) * 16 + fq * 4;
            float p = fmaxf(s[0], 0.f) * W5[m]
                    + fmaxf(s[1], 0.f) * W5[m + 1]
                    + fmaxf(s[2], 0.f) * W5[m + 2]
                    + fmaxf(s[3], 0.f) * W5[m + 3];
            p += __shfl_down(p, 32);
            p += __shfl_down(p, 16);
            if (fq == 0) {
                int n = n0 + (t & 3) * 16 + fr;
                atomicAdd(&zbuf[n], p);
            }
        }
    }
}

// ---------------------------------------------------------------------------
// Final loss: sigmoid + weighted squared error, single block.
// ---------------------------------------------------------------------------
__global__ __launch_bounds__(256) void loss_k(
    const float* __restrict__ zbuf, const int* __restrict__ rand_idx,
    float* __restrict__ out)
{
    __shared__ int cnt[32];
    __shared__ float red[256];
    int tid = threadIdx.x;
    if (tid < 32) cnt[tid] = 0;
    __syncthreads();
    if (tid < NEG_N_) atomicAdd(&cnt[rand_idx[tid]], 1);
    __syncthreads();
    float acc = 0.f;
    for (int c = tid; c < NCOL_; c += 256) {
        float s = 1.f / (1.f + expf(-zbuf[c]));
        int c33 = c % 33;
        if (c33 == 0) { float d = s - 1.f; acc += 128.f * d * d; }
        else          { acc += (float)cnt[c33 - 1] * s * s; }
    }
    red[tid] = acc;
    __syncthreads();
    for (int off = 128; off > 0; off >>= 1) {
        if (tid < off) red[tid] += red[tid + off];
        __syncthreads();
    }
    if (tid == 0) out[0] = red[0];
}

extern "C" void kernel_launch(void* const* d_in, const int* in_sizes, int n_in,
                              void* d_out, int out_size, void* d_ws, size_t ws_size,
                              hipStream_t stream)
{
    const int*   doc        = (const int*)d_in[0];
    const float* doc_f      = (const float*)d_in[1];
    const int*   query      = (const int*)d_in[2];
    const int*   target_s   = (const int*)d_in[3];
    const int*   target_e   = (const int*)d_in[4];
    const float* emb        = (const float*)d_in[7];
    const float* W1         = (const float*)d_in[8];
    const float* W2         = (const float*)d_in[9];
    const float* W3         = (const float*)d_in[10];
    const float* W4         = (const float*)d_in[11];
    const float* W5         = (const float*)d_in[12];
    const int*   rand_length   = (const int*)d_in[13];
    const int*   rand_position = (const int*)d_in[14];
    const int*   rand_idx      = (const int*)d_in[15];

    char* ws = (char*)d_ws;
    size_t off = 0;
    auto alloc = [&](size_t bytes) {
        void* p = ws + off;
        off = (off + bytes + 255) & ~(size_t)255;
        return p;
    };
    unsigned short* W1b = (unsigned short*)alloc((size_t)1024 * KP1_ * 2);
    unsigned short* W2b = (unsigned short*)alloc((size_t)1024 * 1024 * 2);
    unsigned short* W3b = (unsigned short*)alloc((size_t)1024 * 1024 * 2);
    unsigned short* W4b = (unsigned short*)alloc((size_t)512 * 1024 * 2);
    unsigned short* Ft  = (unsigned short*)alloc((size_t)NPAD_ * KP1_ * 2);
    unsigned short* hA  = (unsigned short*)alloc((size_t)NPAD_ * 1024 * 2);
    unsigned short* hB  = (unsigned short*)alloc((size_t)NPAD_ * 1024 * 2);
    float* zbuf         = (float*)alloc((size_t)NPAD_ * sizeof(float));
    float* d_loss = (float*)d_out;
    (void)ws_size; (void)in_sizes; (void)n_in; (void)out_size;

    prep<<<dim3(2033), dim3(320), 0, stream>>>(
        doc, doc_f, query, target_s, target_e, emb,
        rand_length, rand_position,
        W1, W2, W3, W4, W1b, W2b, W3b, W4b, Ft, zbuf);

    gemm_relu<<<dim3(16, 17), dim3(256), 0, stream>>>(W1b, Ft, hA, 1024, KP1_);
    gemm_relu<<<dim3(16, 17), dim3(256), 0, stream>>>(W2b, hA, hB, 1024, 1024);
    gemm_relu<<<dim3(16, 17), dim3(256), 0, stream>>>(W3b, hB, hA, 1024, 1024);
    gemm4_score<<<dim3(8, 17), dim3(256), 0, stream>>>(W4b, hA, W5, zbuf, 512, 1024);

    loss_k<<<dim3(1), dim3(256), 0, stream>>>(zbuf, rand_idx, d_loss);
}